// Round 1
// baseline (447.002 us; speedup 1.0000x reference)
//
#include <hip/hip_runtime.h>

#define NTOT 262144   // B*L
#define NLAY 8
#define SEGOUT 112    // useful nodes per 64-lane wave (128 nodes incl. 8+8 halo)
#define NSEG ((NTOT + SEGOUT - 1) / SEGOUT)   // 2341

// silu via v_rcp_f32: harness compiles WITHOUT fast-math, so 1.0f/x emits the
// full IEEE divide expansion (~10 VALU ops). v_rcp is 1 op, ~1 ulp — noise vs
// the 2.4e-4 absmax budget. Same for v_sqrt.
__device__ __forceinline__ float silu_f(float x) {
    return x * __builtin_amdgcn_rcpf(1.0f + __expf(-x));
}

// ---------------- Kernel 1: encode  (mask/pos -> h0, pos0) ----------------
__global__ __launch_bounds__(256) void k_encode(
    const float* __restrict__ ap, const float* __restrict__ amask,
    const float* __restrict__ embW, const float* __restrict__ embB,
    const float* __restrict__ peW1, const float* __restrict__ peB1,
    const float* __restrict__ peW2, const float* __restrict__ peB2,
    float* __restrict__ h0, float* __restrict__ pos0)
{
    __shared__ alignas(16) float sM[64 * 37];
    __shared__ alignas(16) float sA[64 * 111];
    __shared__ alignas(16) float sW[37 * 8];     // embW staged (296 floats)
    const int tid = threadIdx.x;
    const long nb = (long)blockIdx.x * 64;

    if (tid < 74) ((float4*)sW)[tid] = ((const float4*)embW)[tid];
    const float4* gm = (const float4*)(amask + nb * 37);
    float4* sm4 = (float4*)sM;
    #pragma unroll 1
    for (int i = tid; i < 64 * 37 / 4; i += 256) sm4[i] = gm[i];
    const float4* ga = (const float4*)(ap + nb * 111);
    float4* sa4 = (float4*)sA;
    #pragma unroll 1
    for (int i = tid; i < 64 * 111 / 4; i += 256) sa4[i] = ga[i];
    __syncthreads();

    const int n = tid >> 2;          // node within block
    const int p = tid & 3;           // quad lane
    const int k0 = p * 10;
    const int k1 = (p == 3) ? 37 : k0 + 10;

    const float* mrow = sM + n * 37;
    const float* arow = sA + n * 111;
    float hacc[8] = {0, 0, 0, 0, 0, 0, 0, 0};
    float ps0 = 0.f, ps1 = 0.f, ps2 = 0.f, msum = 0.f;
    #pragma unroll 1
    for (int k = k0; k < k1; ++k) {
        float mv = mrow[k];
        msum += mv;
        const float4* wr = (const float4*)(sW + k * 8);
        float4 w0 = wr[0], w1 = wr[1];
        hacc[0] += mv * w0.x; hacc[1] += mv * w0.y;
        hacc[2] += mv * w0.z; hacc[3] += mv * w0.w;
        hacc[4] += mv * w1.x; hacc[5] += mv * w1.y;
        hacc[6] += mv * w1.z; hacc[7] += mv * w1.w;
        ps0 += mv * arow[k * 3 + 0];
        ps1 += mv * arow[k * 3 + 1];
        ps2 += mv * arow[k * 3 + 2];
    }
    #pragma unroll
    for (int m = 1; m <= 2; m <<= 1) {
        msum += __shfl_xor(msum, m);
        ps0 += __shfl_xor(ps0, m);
        ps1 += __shfl_xor(ps1, m);
        ps2 += __shfl_xor(ps2, m);
        #pragma unroll
        for (int j = 0; j < 8; ++j) hacc[j] += __shfl_xor(hacc[j], m);
    }

    float inv = __builtin_amdgcn_rcpf(msum + 1e-8f);
    float mp0 = ps0 * inv, mp1 = ps1 * inv, mp2 = ps2 * inv;
    float q[8];
    #pragma unroll
    for (int j = 0; j < 8; ++j) {
        float a = peB1[j];
        a += mp0 * peW1[0 * 8 + j];
        a += mp1 * peW1[1 * 8 + j];
        a += mp2 * peW1[2 * 8 + j];
        q[j] = silu_f(a);
    }
    #pragma unroll
    for (int j = 0; j < 8; ++j) {
        float a = peB2[j] + embB[j];
        #pragma unroll
        for (int r = 0; r < 8; ++r) a += q[r] * peW2[r * 8 + j];
        hacc[j] += a;
    }
    const long g = nb + n;
    if (p == 0) ((float4*)(h0 + g * 8))[0] = make_float4(hacc[0], hacc[1], hacc[2], hacc[3]);
    if (p == 1) ((float4*)(h0 + g * 8))[1] = make_float4(hacc[4], hacc[5], hacc[6], hacc[7]);
    if (p == 2) ((float4*)pos0)[g] = make_float4(mp0, mp1, mp2, 0.f);
}

// ---------------- Kernel 2: fused 8-layer SE3 stack + mid latent ----------
// Wave-autonomous rewrite: each 64-lane wave owns a 128-node segment
// (2 nodes/lane), halo 8 each side shrinks 1/layer. Neighbor exchange via
// __shfl (+-1 lane), so NO __syncthreads and NO LDS in the layer loop.
// Garbage propagates inward exactly 1 node/layer from the wave edges, which
// the 8-node halo absorbs; the real chain ends (g==0, g==NTOT-1) are handled
// by the edge-existence guards which coincide with valid data.

__device__ __forceinline__ void edge_mlp(
    const float* __restrict__ wE1, const float* __restrict__ bE1,
    const float* __restrict__ wE2, const float* __restrict__ bE2,
    const float* __restrict__ wP1, const float* __restrict__ bP1,
    const float* __restrict__ wP2,
    const float* hl, const float* hr, float r0, float r1, float r2,
    float* ea, float& dp0, float& dp1, float& dp2)
{
    float dist = __builtin_amdgcn_sqrtf(r0 * r0 + r1 * r1 + r2 * r2);
    float t1[8];
    #pragma unroll
    for (int j = 0; j < 8; ++j) {
        float a = bE1[j];
        #pragma unroll
        for (int r = 0; r < 8; ++r) a += hl[r] * wE1[r * 8 + j];
        #pragma unroll
        for (int r = 0; r < 8; ++r) a += hr[r] * wE1[64 + r * 8 + j];
        a += dist * wE1[128 + j];
        t1[j] = silu_f(a);
    }
    #pragma unroll
    for (int j = 0; j < 8; ++j) {
        float a = bE2[j];
        #pragma unroll
        for (int r = 0; r < 8; ++r) a += t1[r] * wE2[r * 8 + j];
        ea[j] = a;
    }
    float q[8];
    #pragma unroll
    for (int j = 0; j < 8; ++j) {
        float a = bP1[j];
        #pragma unroll
        for (int r = 0; r < 8; ++r) a += ea[r] * wP1[r * 8 + j];
        q[j] = silu_f(a);
    }
    dp0 = 0.f; dp1 = 0.f; dp2 = 0.f;
    #pragma unroll
    for (int r = 0; r < 8; ++r) {
        dp0 += q[r] * wP2[r * 3 + 0];
        dp1 += q[r] * wP2[r * 3 + 1];
        dp2 += q[r] * wP2[r * 3 + 2];
    }
}

__device__ __forceinline__ void node_mlp(
    const float* __restrict__ wN1, const float* __restrict__ bN1,
    const float* __restrict__ wN2, const float* __restrict__ bN2,
    const float* hl, const float* nu, float* hn)
{
    float u[8];
    #pragma unroll
    for (int j = 0; j < 8; ++j) {
        float a = bN1[j];
        #pragma unroll
        for (int r = 0; r < 8; ++r) a += hl[r] * wN1[r * 8 + j];
        #pragma unroll
        for (int r = 0; r < 8; ++r) a += nu[r] * wN1[64 + r * 8 + j];
        u[j] = silu_f(a);
    }
    #pragma unroll
    for (int j = 0; j < 8; ++j) {
        float a = bN2[j];
        #pragma unroll
        for (int r = 0; r < 8; ++r) a += u[r] * wN2[r * 8 + j];
        hn[j] = a;
    }
}

__device__ __forceinline__ void latent_mlp(
    const float* __restrict__ tW1, const float* __restrict__ tB1,
    const float* __restrict__ tW2, const float* __restrict__ tB2,
    const float* __restrict__ fW1, const float* __restrict__ fB1,
    const float* __restrict__ fW2, const float* __restrict__ fB2,
    float* hn)
{
    float a8[8];
    #pragma unroll
    for (int j = 0; j < 8; ++j) {
        float a = tB1[j];
        #pragma unroll
        for (int r = 0; r < 8; ++r) a += hn[r] * tW1[r * 8 + j];
        a8[j] = silu_f(a);
    }
    float zz[8];
    #pragma unroll
    for (int j = 0; j < 8; ++j) {
        float a = tB2[j];
        #pragma unroll
        for (int r = 0; r < 8; ++r) a += a8[r] * tW2[r * 8 + j];
        zz[j] = a;
    }
    float b8[8];
    #pragma unroll
    for (int j = 0; j < 8; ++j) {
        float a = fB1[j];
        #pragma unroll
        for (int r = 0; r < 8; ++r) a += zz[r] * fW1[r * 8 + j];
        b8[j] = silu_f(a);
    }
    #pragma unroll
    for (int j = 0; j < 8; ++j) {
        float a = fB2[j];
        #pragma unroll
        for (int r = 0; r < 8; ++r) a += b8[r] * fW2[r * 8 + j];
        hn[j] = a;
    }
}

__global__ __launch_bounds__(256) void k_stack(
    const float* __restrict__ h0, const float* __restrict__ pos0,
    float* __restrict__ hfin,
    const float* __restrict__ ceW1, const float* __restrict__ ceB1,
    const float* __restrict__ ceW2, const float* __restrict__ ceB2,
    const float* __restrict__ cpW1, const float* __restrict__ cpB1,
    const float* __restrict__ cpW2,
    const float* __restrict__ cnW1, const float* __restrict__ cnB1,
    const float* __restrict__ cnW2, const float* __restrict__ cnB2,
    const float* __restrict__ tW1, const float* __restrict__ tB1,
    const float* __restrict__ tW2, const float* __restrict__ tB2,
    const float* __restrict__ fW1, const float* __restrict__ fB1,
    const float* __restrict__ fW2, const float* __restrict__ fB2)
{
    const int lane = threadIdx.x & 63;
    const int seg  = blockIdx.x * 4 + (threadIdx.x >> 6);
    const int base = seg * SEGOUT - 8;          // first node of this wave's window
    const int nA   = base + 2 * lane;           // this lane's even node
    const int nB   = nA + 1;                    // this lane's odd node

    float hA[8] = {0, 0, 0, 0, 0, 0, 0, 0};
    float hB[8] = {0, 0, 0, 0, 0, 0, 0, 0};
    float pA0 = 0.f, pA1 = 0.f, pA2 = 0.f;
    float pB0 = 0.f, pB1 = 0.f, pB2 = 0.f;
    if (nA >= 0 && nA < NTOT) {
        const float4* hp = (const float4*)(h0 + (long)nA * 8);
        float4 a = hp[0], b = hp[1];
        hA[0] = a.x; hA[1] = a.y; hA[2] = a.z; hA[3] = a.w;
        hA[4] = b.x; hA[5] = b.y; hA[6] = b.z; hA[7] = b.w;
        float4 p = ((const float4*)pos0)[nA];
        pA0 = p.x; pA1 = p.y; pA2 = p.z;
    }
    if (nB >= 0 && nB < NTOT) {
        const float4* hp = (const float4*)(h0 + (long)nB * 8);
        float4 a = hp[0], b = hp[1];
        hB[0] = a.x; hB[1] = a.y; hB[2] = a.z; hB[3] = a.w;
        hB[4] = b.x; hB[5] = b.y; hB[6] = b.z; hB[7] = b.w;
        float4 p = ((const float4*)pos0)[nB];
        pB0 = p.x; pB1 = p.y; pB2 = p.z;
    }

    const bool eA = (nA >= 0) && (nB < NTOT);          // edge (nA, nB)
    const bool eB = (nB >= 0) && (nB + 1 < NTOT);      // edge (nB, nC)
    const bool eL = (nA >= 1) && (nA < NTOT);          // edge (nA-1, nA)

    #pragma unroll 1
    for (int li = 0; li < NLAY; ++li) {
        const float* wE1 = ceW1 + li * 136;
        const float* bE1 = ceB1 + li * 8;
        const float* wE2 = ceW2 + li * 64;
        const float* bE2 = ceB2 + li * 8;
        const float* wP1 = cpW1 + li * 64;
        const float* bP1 = cpB1 + li * 8;
        const float* wP2 = cpW2 + li * 24;
        const float* wN1 = cnW1 + li * 128;
        const float* bN1 = cnB1 + li * 8;
        const float* wN2 = cnW2 + li * 64;
        const float* bN2 = cnB2 + li * 8;

        // neighbor C = next lane's node A
        float hc[8], pc0, pc1, pc2;
        #pragma unroll
        for (int j = 0; j < 8; ++j) hc[j] = __shfl_down(hA[j], 1);
        pc0 = __shfl_down(pA0, 1);
        pc1 = __shfl_down(pA1, 1);
        pc2 = __shfl_down(pA2, 1);

        float eaA[8], dpA0, dpA1, dpA2;
        edge_mlp(wE1, bE1, wE2, bE2, wP1, bP1, wP2,
                 hA, hB, pB0 - pA0, pB1 - pA1, pB2 - pA2, eaA, dpA0, dpA1, dpA2);
        float eaB[8], dpB0, dpB1, dpB2;
        edge_mlp(wE1, bE1, wE2, bE2, wP1, bP1, wP2,
                 hB, hc, pc0 - pB0, pc1 - pB1, pc2 - pB2, eaB, dpB0, dpB1, dpB2);

        // left edge of node A = previous lane's edge B
        float eaL[8], dpL0, dpL1, dpL2;
        #pragma unroll
        for (int j = 0; j < 8; ++j) eaL[j] = __shfl_up(eaB[j], 1);
        dpL0 = __shfl_up(dpB0, 1);
        dpL1 = __shfl_up(dpB1, 1);
        dpL2 = __shfl_up(dpB2, 1);

        float nuA[8], nuB[8];
        #pragma unroll
        for (int j = 0; j < 8; ++j) {
            nuA[j] = (eA ? eaA[j] : 0.f) + (eL ? eaL[j] : 0.f);
            nuB[j] = (eB ? eaB[j] : 0.f) + (eA ? eaA[j] : 0.f);
        }
        float puA0 = (eA ? dpA0 : 0.f) - (eL ? dpL0 : 0.f);
        float puA1 = (eA ? dpA1 : 0.f) - (eL ? dpL1 : 0.f);
        float puA2 = (eA ? dpA2 : 0.f) - (eL ? dpL2 : 0.f);
        float puB0 = (eB ? dpB0 : 0.f) - (eA ? dpA0 : 0.f);
        float puB1 = (eB ? dpB1 : 0.f) - (eA ? dpA1 : 0.f);
        float puB2 = (eB ? dpB2 : 0.f) - (eA ? dpA2 : 0.f);

        float hnA[8], hnB[8];
        node_mlp(wN1, bN1, wN2, bN2, hA, nuA, hnA);
        node_mlp(wN1, bN1, wN2, bN2, hB, nuB, hnB);

        pA0 += 0.1f * puA0; pA1 += 0.1f * puA1; pA2 += 0.1f * puA2;
        pB0 += 0.1f * puB0; pB1 += 0.1f * puB1; pB2 += 0.1f * puB2;

        if (li == 3) {
            latent_mlp(tW1, tB1, tW2, tB2, fW1, fB1, fW2, fB2, hnA);
            latent_mlp(tW1, tB1, tW2, tB2, fW1, fB1, fW2, fB2, hnB);
        }

        #pragma unroll
        for (int j = 0; j < 8; ++j) { hA[j] = hnA[j]; hB[j] = hnB[j]; }
    }

    // valid output = lanes 4..59 (halo 8 nodes each side consumed by 8 layers)
    if (lane >= 4 && lane < 60) {
        if (nA < NTOT) {
            float4* hd = (float4*)(hfin + (long)nA * 8);
            hd[0] = make_float4(hA[0], hA[1], hA[2], hA[3]);
            hd[1] = make_float4(hA[4], hA[5], hA[6], hA[7]);
        }
        if (nB < NTOT) {
            float4* hd = (float4*)(hfin + (long)nB * 8);
            hd[0] = make_float4(hB[0], hB[1], hB[2], hB[3]);
            hd[1] = make_float4(hB[4], hB[5], hB[6], hB[7]);
        }
    }
}

// ---------------- Kernel 3: decode (h -> pos_out, mask_out) ---------------
__global__ __launch_bounds__(256) void k_decode(
    const float* __restrict__ hfin,
    const float* __restrict__ dW1, const float* __restrict__ dB1,
    const float* __restrict__ dW2, const float* __restrict__ dB2,
    const float* __restrict__ mW, const float* __restrict__ mB,
    float* __restrict__ out)
{
    __shared__ alignas(16) float sh[128 * 8];
    __shared__ alignas(16) float st1[128 * 16];
    const int tid = threadIdx.x;
    const long nb = (long)blockIdx.x * 128;

    ((float4*)sh)[tid] = ((const float4*)(hfin + nb * 8))[tid];
    __syncthreads();

    {   // t1 = silu(h @ posdec_W1 + b1): 2 threads per node, 8 cols each
        const int n = tid >> 1;
        const int c0 = (tid & 1) * 8;
        const float4* h4 = (const float4*)(sh + n * 8);
        float4 h0v = h4[0], h1v = h4[1];
        float hr[8] = {h0v.x, h0v.y, h0v.z, h0v.w, h1v.x, h1v.y, h1v.z, h1v.w};
        #pragma unroll
        for (int jj = 0; jj < 8; ++jj) {
            int j = c0 + jj;
            float a = dB1[j];
            #pragma unroll
            for (int r = 0; r < 8; ++r) a += hr[r] * dW1[r * 16 + j];
            st1[n * 16 + j] = silu_f(a);
        }
    }
    __syncthreads();

    if (tid < 222) {
        // ---- pos_out: column-stationary, 2 node-phases ----
        const int half = (tid >= 111) ? 1 : 0;
        const int j = tid - half * 111;
        float w[16];
        #pragma unroll
        for (int r = 0; r < 16; ++r) w[r] = dW2[r * 111 + j];
        const float bj = dB2[j];
        float* op = out + nb * 111 + j;
        #pragma unroll 2
        for (int n = half; n < 128; n += 2) {
            const float4* t4 = (const float4*)(st1 + n * 16);
            float4 a0 = t4[0], a1 = t4[1], a2 = t4[2], a3 = t4[3];
            float acc = bj;
            acc += a0.x * w[0] + a0.y * w[1] + a0.z * w[2] + a0.w * w[3];
            acc += a1.x * w[4] + a1.y * w[5] + a1.z * w[6] + a1.w * w[7];
            acc += a2.x * w[8] + a2.y * w[9] + a2.z * w[10] + a2.w * w[11];
            acc += a3.x * w[12] + a3.y * w[13] + a3.z * w[14] + a3.w * w[15];
            op[n * 111] = acc;
        }
        // ---- mask_out: column-stationary, 6 node-phases ----
        const int g6 = tid / 37;      // 0..5
        const int j2 = tid - g6 * 37;
        float wm[8];
        #pragma unroll
        for (int r = 0; r < 8; ++r) wm[r] = mW[r * 37 + j2];
        const float bm = mB[j2];
        float* omp_ = out + (long)NTOT * 111 + nb * 37 + j2;
        #pragma unroll 1
        for (int n = g6; n < 128; n += 6) {
            const float4* h4 = (const float4*)(sh + n * 8);
            float4 h0v = h4[0], h1v = h4[1];
            float acc = bm;
            acc += h0v.x * wm[0] + h0v.y * wm[1] + h0v.z * wm[2] + h0v.w * wm[3];
            acc += h1v.x * wm[4] + h1v.y * wm[5] + h1v.z * wm[6] + h1v.w * wm[7];
            omp_[n * 37] = acc;
        }
    }
}

extern "C" void kernel_launch(void* const* d_in, const int* in_sizes, int n_in,
                              void* d_out, int out_size, void* d_ws, size_t ws_size,
                              hipStream_t stream) {
    const float* ap     = (const float*)d_in[0];
    const float* amask  = (const float*)d_in[1];
    const float* embW   = (const float*)d_in[2];
    const float* embB   = (const float*)d_in[3];
    const float* peW1   = (const float*)d_in[4];
    const float* peB1   = (const float*)d_in[5];
    const float* peW2   = (const float*)d_in[6];
    const float* peB2   = (const float*)d_in[7];
    const float* ceW1   = (const float*)d_in[8];
    const float* ceB1   = (const float*)d_in[9];
    const float* ceW2   = (const float*)d_in[10];
    const float* ceB2   = (const float*)d_in[11];
    const float* cpW1   = (const float*)d_in[12];
    const float* cpB1   = (const float*)d_in[13];
    const float* cpW2   = (const float*)d_in[14];
    const float* cnW1   = (const float*)d_in[15];
    const float* cnB1   = (const float*)d_in[16];
    const float* cnW2   = (const float*)d_in[17];
    const float* cnB2   = (const float*)d_in[18];
    const float* tW1    = (const float*)d_in[19];
    const float* tB1    = (const float*)d_in[20];
    const float* tW2    = (const float*)d_in[21];
    const float* tB2    = (const float*)d_in[22];
    const float* fW1    = (const float*)d_in[23];
    const float* fB1    = (const float*)d_in[24];
    const float* fW2    = (const float*)d_in[25];
    const float* fB2    = (const float*)d_in[26];
    const float* dW1    = (const float*)d_in[27];
    const float* dB1    = (const float*)d_in[28];
    const float* dW2    = (const float*)d_in[29];
    const float* dB2    = (const float*)d_in[30];
    const float* mW     = (const float*)d_in[31];
    const float* mB     = (const float*)d_in[32];

    float* h0   = (float*)d_ws;
    float* pos0 = h0 + (size_t)NTOT * 8;
    float* hfin = pos0 + (size_t)NTOT * 4;
    float* out  = (float*)d_out;

    k_encode<<<NTOT / 64, 256, 0, stream>>>(ap, amask, embW, embB,
                                            peW1, peB1, peW2, peB2, h0, pos0);
    const int nblk = (NSEG + 3) / 4;   // 4 waves per 256-thread block
    k_stack<<<nblk, 256, 0, stream>>>(
        h0, pos0, hfin,
        ceW1, ceB1, ceW2, ceB2, cpW1, cpB1, cpW2,
        cnW1, cnB1, cnW2, cnB2,
        tW1, tB1, tW2, tB2, fW1, fB1, fW2, fB2);
    k_decode<<<NTOT / 128, 256, 0, stream>>>(hfin, dW1, dB1, dW2, dB2, mW, mB, out);
}

// Round 2
// 432.446 us; speedup vs baseline: 1.0337x; 1.0337x over previous
//
#include <hip/hip_runtime.h>

#define NTOT 262144   // B*L
#define NLAY 8
#define SEGOUT 48     // useful nodes per 64-lane wave (64 nodes incl. 8+8 halo)
#define NSEG ((NTOT + SEGOUT - 1) / SEGOUT)   // 5462

// silu via v_rcp_f32: harness compiles WITHOUT fast-math, so 1.0f/x emits the
// full IEEE divide expansion (~10 VALU ops). v_rcp is 1 op, ~1 ulp — noise vs
// the 2.4e-4 absmax budget. Same for v_sqrt.
__device__ __forceinline__ float silu_f(float x) {
    return x * __builtin_amdgcn_rcpf(1.0f + __expf(-x));
}

// ---------------- Kernel 1: encode  (mask/pos -> h0, pos0) ----------------
__global__ __launch_bounds__(256) void k_encode(
    const float* __restrict__ ap, const float* __restrict__ amask,
    const float* __restrict__ embW, const float* __restrict__ embB,
    const float* __restrict__ peW1, const float* __restrict__ peB1,
    const float* __restrict__ peW2, const float* __restrict__ peB2,
    float* __restrict__ h0, float* __restrict__ pos0)
{
    __shared__ alignas(16) float sM[64 * 37];
    __shared__ alignas(16) float sA[64 * 111];
    __shared__ alignas(16) float sW[37 * 8];     // embW staged (296 floats)
    const int tid = threadIdx.x;
    const long nb = (long)blockIdx.x * 64;

    if (tid < 74) ((float4*)sW)[tid] = ((const float4*)embW)[tid];
    const float4* gm = (const float4*)(amask + nb * 37);
    float4* sm4 = (float4*)sM;
    #pragma unroll 1
    for (int i = tid; i < 64 * 37 / 4; i += 256) sm4[i] = gm[i];
    const float4* ga = (const float4*)(ap + nb * 111);
    float4* sa4 = (float4*)sA;
    #pragma unroll 1
    for (int i = tid; i < 64 * 111 / 4; i += 256) sa4[i] = ga[i];
    __syncthreads();

    const int n = tid >> 2;          // node within block
    const int p = tid & 3;           // quad lane
    const int k0 = p * 10;
    const int k1 = (p == 3) ? 37 : k0 + 10;

    const float* mrow = sM + n * 37;
    const float* arow = sA + n * 111;
    float hacc[8] = {0, 0, 0, 0, 0, 0, 0, 0};
    float ps0 = 0.f, ps1 = 0.f, ps2 = 0.f, msum = 0.f;
    #pragma unroll 1
    for (int k = k0; k < k1; ++k) {
        float mv = mrow[k];
        msum += mv;
        const float4* wr = (const float4*)(sW + k * 8);
        float4 w0 = wr[0], w1 = wr[1];
        hacc[0] += mv * w0.x; hacc[1] += mv * w0.y;
        hacc[2] += mv * w0.z; hacc[3] += mv * w0.w;
        hacc[4] += mv * w1.x; hacc[5] += mv * w1.y;
        hacc[6] += mv * w1.z; hacc[7] += mv * w1.w;
        ps0 += mv * arow[k * 3 + 0];
        ps1 += mv * arow[k * 3 + 1];
        ps2 += mv * arow[k * 3 + 2];
    }
    #pragma unroll
    for (int m = 1; m <= 2; m <<= 1) {
        msum += __shfl_xor(msum, m);
        ps0 += __shfl_xor(ps0, m);
        ps1 += __shfl_xor(ps1, m);
        ps2 += __shfl_xor(ps2, m);
        #pragma unroll
        for (int j = 0; j < 8; ++j) hacc[j] += __shfl_xor(hacc[j], m);
    }

    float inv = __builtin_amdgcn_rcpf(msum + 1e-8f);
    float mp0 = ps0 * inv, mp1 = ps1 * inv, mp2 = ps2 * inv;
    float q[8];
    #pragma unroll
    for (int j = 0; j < 8; ++j) {
        float a = peB1[j];
        a += mp0 * peW1[0 * 8 + j];
        a += mp1 * peW1[1 * 8 + j];
        a += mp2 * peW1[2 * 8 + j];
        q[j] = silu_f(a);
    }
    #pragma unroll
    for (int j = 0; j < 8; ++j) {
        float a = peB2[j] + embB[j];
        #pragma unroll
        for (int r = 0; r < 8; ++r) a += q[r] * peW2[r * 8 + j];
        hacc[j] += a;
    }
    const long g = nb + n;
    if (p == 0) ((float4*)(h0 + g * 8))[0] = make_float4(hacc[0], hacc[1], hacc[2], hacc[3]);
    if (p == 1) ((float4*)(h0 + g * 8))[1] = make_float4(hacc[4], hacc[5], hacc[6], hacc[7]);
    if (p == 2) ((float4*)pos0)[g] = make_float4(mp0, mp1, mp2, 0.f);
}

// ---------------- Kernel 2: fused 8-layer SE3 stack + mid latent ----------
// Wave-autonomous, 1 node per lane: each 64-lane wave owns a 64-node window,
// halo 8 each side shrinks 1/layer -> 48 useful nodes/wave. This doubles the
// wave count vs 2-nodes/lane (5462 waves = ~21/CU) to fix the grid-size
// occupancy cap (was 9 waves/CU, 25% occupancy, VALUBusy 38%).
// Neighbor exchange via __shfl (+-1 lane): NO __syncthreads, NO LDS.

__device__ __forceinline__ void edge_mlp(
    const float* __restrict__ wE1, const float* __restrict__ bE1,
    const float* __restrict__ wE2, const float* __restrict__ bE2,
    const float* __restrict__ wP1, const float* __restrict__ bP1,
    const float* __restrict__ wP2,
    const float* hl, const float* hr, float r0, float r1, float r2,
    float* ea, float& dp0, float& dp1, float& dp2)
{
    float dist = __builtin_amdgcn_sqrtf(r0 * r0 + r1 * r1 + r2 * r2);
    float t1[8];
    #pragma unroll
    for (int j = 0; j < 8; ++j) {
        float a = bE1[j];
        #pragma unroll
        for (int r = 0; r < 8; ++r) a += hl[r] * wE1[r * 8 + j];
        #pragma unroll
        for (int r = 0; r < 8; ++r) a += hr[r] * wE1[64 + r * 8 + j];
        a += dist * wE1[128 + j];
        t1[j] = silu_f(a);
    }
    #pragma unroll
    for (int j = 0; j < 8; ++j) {
        float a = bE2[j];
        #pragma unroll
        for (int r = 0; r < 8; ++r) a += t1[r] * wE2[r * 8 + j];
        ea[j] = a;
    }
    float q[8];
    #pragma unroll
    for (int j = 0; j < 8; ++j) {
        float a = bP1[j];
        #pragma unroll
        for (int r = 0; r < 8; ++r) a += ea[r] * wP1[r * 8 + j];
        q[j] = silu_f(a);
    }
    dp0 = 0.f; dp1 = 0.f; dp2 = 0.f;
    #pragma unroll
    for (int r = 0; r < 8; ++r) {
        dp0 += q[r] * wP2[r * 3 + 0];
        dp1 += q[r] * wP2[r * 3 + 1];
        dp2 += q[r] * wP2[r * 3 + 2];
    }
}

__device__ __forceinline__ void node_mlp(
    const float* __restrict__ wN1, const float* __restrict__ bN1,
    const float* __restrict__ wN2, const float* __restrict__ bN2,
    const float* hl, const float* nu, float* hn)
{
    float u[8];
    #pragma unroll
    for (int j = 0; j < 8; ++j) {
        float a = bN1[j];
        #pragma unroll
        for (int r = 0; r < 8; ++r) a += hl[r] * wN1[r * 8 + j];
        #pragma unroll
        for (int r = 0; r < 8; ++r) a += nu[r] * wN1[64 + r * 8 + j];
        u[j] = silu_f(a);
    }
    #pragma unroll
    for (int j = 0; j < 8; ++j) {
        float a = bN2[j];
        #pragma unroll
        for (int r = 0; r < 8; ++r) a += u[r] * wN2[r * 8 + j];
        hn[j] = a;
    }
}

__device__ __forceinline__ void latent_mlp(
    const float* __restrict__ tW1, const float* __restrict__ tB1,
    const float* __restrict__ tW2, const float* __restrict__ tB2,
    const float* __restrict__ fW1, const float* __restrict__ fB1,
    const float* __restrict__ fW2, const float* __restrict__ fB2,
    float* hn)
{
    float a8[8];
    #pragma unroll
    for (int j = 0; j < 8; ++j) {
        float a = tB1[j];
        #pragma unroll
        for (int r = 0; r < 8; ++r) a += hn[r] * tW1[r * 8 + j];
        a8[j] = silu_f(a);
    }
    float zz[8];
    #pragma unroll
    for (int j = 0; j < 8; ++j) {
        float a = tB2[j];
        #pragma unroll
        for (int r = 0; r < 8; ++r) a += a8[r] * tW2[r * 8 + j];
        zz[j] = a;
    }
    float b8[8];
    #pragma unroll
    for (int j = 0; j < 8; ++j) {
        float a = fB1[j];
        #pragma unroll
        for (int r = 0; r < 8; ++r) a += zz[r] * fW1[r * 8 + j];
        b8[j] = silu_f(a);
    }
    #pragma unroll
    for (int j = 0; j < 8; ++j) {
        float a = fB2[j];
        #pragma unroll
        for (int r = 0; r < 8; ++r) a += b8[r] * fW2[r * 8 + j];
        hn[j] = a;
    }
}

__global__ __launch_bounds__(256) void k_stack(
    const float* __restrict__ h0, const float* __restrict__ pos0,
    float* __restrict__ hfin,
    const float* __restrict__ ceW1, const float* __restrict__ ceB1,
    const float* __restrict__ ceW2, const float* __restrict__ ceB2,
    const float* __restrict__ cpW1, const float* __restrict__ cpB1,
    const float* __restrict__ cpW2,
    const float* __restrict__ cnW1, const float* __restrict__ cnB1,
    const float* __restrict__ cnW2, const float* __restrict__ cnB2,
    const float* __restrict__ tW1, const float* __restrict__ tB1,
    const float* __restrict__ tW2, const float* __restrict__ tB2,
    const float* __restrict__ fW1, const float* __restrict__ fB1,
    const float* __restrict__ fW2, const float* __restrict__ fB2)
{
    const int lane = threadIdx.x & 63;
    const int seg  = blockIdx.x * 4 + (threadIdx.x >> 6);
    const int base = seg * SEGOUT - 8;          // first node of this wave's window
    const int n    = base + lane;               // this lane's node

    float h[8] = {0, 0, 0, 0, 0, 0, 0, 0};
    float p0 = 0.f, p1 = 0.f, p2 = 0.f;
    if (n >= 0 && n < NTOT) {
        const float4* hp = (const float4*)(h0 + (long)n * 8);
        float4 a = hp[0], b = hp[1];
        h[0] = a.x; h[1] = a.y; h[2] = a.z; h[3] = a.w;
        h[4] = b.x; h[5] = b.y; h[6] = b.z; h[7] = b.w;
        float4 p = ((const float4*)pos0)[n];
        p0 = p.x; p1 = p.y; p2 = p.z;
    }

    const bool eR = (n >= 0) && (n + 1 < NTOT);   // edge (n, n+1) exists
    const bool eL = (n >= 1) && (n < NTOT);       // edge (n-1, n) exists

    #pragma unroll 1
    for (int li = 0; li < NLAY; ++li) {
        const float* wE1 = ceW1 + li * 136;
        const float* bE1 = ceB1 + li * 8;
        const float* wE2 = ceW2 + li * 64;
        const float* bE2 = ceB2 + li * 8;
        const float* wP1 = cpW1 + li * 64;
        const float* bP1 = cpB1 + li * 8;
        const float* wP2 = cpW2 + li * 24;
        const float* wN1 = cnW1 + li * 128;
        const float* bN1 = cnB1 + li * 8;
        const float* wN2 = cnW2 + li * 64;
        const float* bN2 = cnB2 + li * 8;

        // right neighbor = next lane's node
        float hr[8], pr0, pr1, pr2;
        #pragma unroll
        for (int j = 0; j < 8; ++j) hr[j] = __shfl_down(h[j], 1);
        pr0 = __shfl_down(p0, 1);
        pr1 = __shfl_down(p1, 1);
        pr2 = __shfl_down(p2, 1);

        float ea[8], dp0, dp1, dp2;
        edge_mlp(wE1, bE1, wE2, bE2, wP1, bP1, wP2,
                 h, hr, pr0 - p0, pr1 - p1, pr2 - p2, ea, dp0, dp1, dp2);

        // left edge of node n = previous lane's edge
        float eaL[8], dl0, dl1, dl2;
        #pragma unroll
        for (int j = 0; j < 8; ++j) eaL[j] = __shfl_up(ea[j], 1);
        dl0 = __shfl_up(dp0, 1);
        dl1 = __shfl_up(dp1, 1);
        dl2 = __shfl_up(dp2, 1);

        float nu[8];
        #pragma unroll
        for (int j = 0; j < 8; ++j)
            nu[j] = (eR ? ea[j] : 0.f) + (eL ? eaL[j] : 0.f);
        float pu0 = (eR ? dp0 : 0.f) - (eL ? dl0 : 0.f);
        float pu1 = (eR ? dp1 : 0.f) - (eL ? dl1 : 0.f);
        float pu2 = (eR ? dp2 : 0.f) - (eL ? dl2 : 0.f);

        float hn[8];
        node_mlp(wN1, bN1, wN2, bN2, h, nu, hn);

        p0 += 0.1f * pu0; p1 += 0.1f * pu1; p2 += 0.1f * pu2;

        if (li == 3) {
            latent_mlp(tW1, tB1, tW2, tB2, fW1, fB1, fW2, fB2, hn);
        }

        #pragma unroll
        for (int j = 0; j < 8; ++j) h[j] = hn[j];
    }

    // valid output = lanes 8..55 (halo 8 each side consumed by 8 layers)
    if (lane >= 8 && lane < 56 && n < NTOT) {
        float4* hd = (float4*)(hfin + (long)n * 8);
        hd[0] = make_float4(h[0], h[1], h[2], h[3]);
        hd[1] = make_float4(h[4], h[5], h[6], h[7]);
    }
}

// ---------------- Kernel 3: decode (h -> pos_out, mask_out) ---------------
__global__ __launch_bounds__(256) void k_decode(
    const float* __restrict__ hfin,
    const float* __restrict__ dW1, const float* __restrict__ dB1,
    const float* __restrict__ dW2, const float* __restrict__ dB2,
    const float* __restrict__ mW, const float* __restrict__ mB,
    float* __restrict__ out)
{
    __shared__ alignas(16) float sh[128 * 8];
    __shared__ alignas(16) float st1[128 * 16];
    const int tid = threadIdx.x;
    const long nb = (long)blockIdx.x * 128;

    ((float4*)sh)[tid] = ((const float4*)(hfin + nb * 8))[tid];
    __syncthreads();

    {   // t1 = silu(h @ posdec_W1 + b1): 2 threads per node, 8 cols each
        const int n = tid >> 1;
        const int c0 = (tid & 1) * 8;
        const float4* h4 = (const float4*)(sh + n * 8);
        float4 h0v = h4[0], h1v = h4[1];
        float hr[8] = {h0v.x, h0v.y, h0v.z, h0v.w, h1v.x, h1v.y, h1v.z, h1v.w};
        #pragma unroll
        for (int jj = 0; jj < 8; ++jj) {
            int j = c0 + jj;
            float a = dB1[j];
            #pragma unroll
            for (int r = 0; r < 8; ++r) a += hr[r] * dW1[r * 16 + j];
            st1[n * 16 + j] = silu_f(a);
        }
    }
    __syncthreads();

    if (tid < 222) {
        // ---- pos_out: column-stationary, 2 node-phases ----
        const int half = (tid >= 111) ? 1 : 0;
        const int j = tid - half * 111;
        float w[16];
        #pragma unroll
        for (int r = 0; r < 16; ++r) w[r] = dW2[r * 111 + j];
        const float bj = dB2[j];
        float* op = out + nb * 111 + j;
        #pragma unroll 2
        for (int n = half; n < 128; n += 2) {
            const float4* t4 = (const float4*)(st1 + n * 16);
            float4 a0 = t4[0], a1 = t4[1], a2 = t4[2], a3 = t4[3];
            float acc = bj;
            acc += a0.x * w[0] + a0.y * w[1] + a0.z * w[2] + a0.w * w[3];
            acc += a1.x * w[4] + a1.y * w[5] + a1.z * w[6] + a1.w * w[7];
            acc += a2.x * w[8] + a2.y * w[9] + a2.z * w[10] + a2.w * w[11];
            acc += a3.x * w[12] + a3.y * w[13] + a3.z * w[14] + a3.w * w[15];
            op[n * 111] = acc;
        }
        // ---- mask_out: column-stationary, 6 node-phases ----
        const int g6 = tid / 37;      // 0..5
        const int j2 = tid - g6 * 37;
        float wm[8];
        #pragma unroll
        for (int r = 0; r < 8; ++r) wm[r] = mW[r * 37 + j2];
        const float bm = mB[j2];
        float* omp_ = out + (long)NTOT * 111 + nb * 37 + j2;
        #pragma unroll 1
        for (int n = g6; n < 128; n += 6) {
            const float4* h4 = (const float4*)(sh + n * 8);
            float4 h0v = h4[0], h1v = h4[1];
            float acc = bm;
            acc += h0v.x * wm[0] + h0v.y * wm[1] + h0v.z * wm[2] + h0v.w * wm[3];
            acc += h1v.x * wm[4] + h1v.y * wm[5] + h1v.z * wm[6] + h1v.w * wm[7];
            omp_[n * 37] = acc;
        }
    }
}

extern "C" void kernel_launch(void* const* d_in, const int* in_sizes, int n_in,
                              void* d_out, int out_size, void* d_ws, size_t ws_size,
                              hipStream_t stream) {
    const float* ap     = (const float*)d_in[0];
    const float* amask  = (const float*)d_in[1];
    const float* embW   = (const float*)d_in[2];
    const float* embB   = (const float*)d_in[3];
    const float* peW1   = (const float*)d_in[4];
    const float* peB1   = (const float*)d_in[5];
    const float* peW2   = (const float*)d_in[6];
    const float* peB2   = (const float*)d_in[7];
    const float* ceW1   = (const float*)d_in[8];
    const float* ceB1   = (const float*)d_in[9];
    const float* ceW2   = (const float*)d_in[10];
    const float* ceB2   = (const float*)d_in[11];
    const float* cpW1   = (const float*)d_in[12];
    const float* cpB1   = (const float*)d_in[13];
    const float* cpW2   = (const float*)d_in[14];
    const float* cnW1   = (const float*)d_in[15];
    const float* cnB1   = (const float*)d_in[16];
    const float* cnW2   = (const float*)d_in[17];
    const float* cnB2   = (const float*)d_in[18];
    const float* tW1    = (const float*)d_in[19];
    const float* tB1    = (const float*)d_in[20];
    const float* tW2    = (const float*)d_in[21];
    const float* tB2    = (const float*)d_in[22];
    const float* fW1    = (const float*)d_in[23];
    const float* fB1    = (const float*)d_in[24];
    const float* fW2    = (const float*)d_in[25];
    const float* fB2    = (const float*)d_in[26];
    const float* dW1    = (const float*)d_in[27];
    const float* dB1    = (const float*)d_in[28];
    const float* dW2    = (const float*)d_in[29];
    const float* dB2    = (const float*)d_in[30];
    const float* mW     = (const float*)d_in[31];
    const float* mB     = (const float*)d_in[32];

    float* h0   = (float*)d_ws;
    float* pos0 = h0 + (size_t)NTOT * 8;
    float* hfin = pos0 + (size_t)NTOT * 4;
    float* out  = (float*)d_out;

    k_encode<<<NTOT / 64, 256, 0, stream>>>(ap, amask, embW, embB,
                                            peW1, peB1, peW2, peB2, h0, pos0);
    const int nblk = (NSEG + 3) / 4;   // 4 waves per 256-thread block
    k_stack<<<nblk, 256, 0, stream>>>(
        h0, pos0, hfin,
        ceW1, ceB1, ceW2, ceB2, cpW1, cpB1, cpW2,
        cnW1, cnB1, cnW2, cnB2,
        tW1, tB1, tW2, tB2, fW1, fB1, fW2, fB2);
    k_decode<<<NTOT / 128, 256, 0, stream>>>(hfin, dW1, dB1, dW2, dB2, mW, mB, out);
}